// Round 10
// baseline (108.707 us; speedup 1.0000x reference)
//
#include <hip/hip_runtime.h>
#include <math.h>

#define DNUM 1024
#define CNUM 32000
#define NT 512             // 8 waves/block
#define R 2                // rows per block
#define GRID2 (DNUM / R)   // 512 blocks for pass-2 kernel
#define GRID1 (GRID2 * 2)  // 1024 blocks for pass-1 kernel (column-split x2)
#define KC 4               // coarse bins (1.35 sigma each), span [-0.5s, +4.9s]
#define KF 8               // fine bins   (0.169 sigma each)
#define NQ (CNUM / 4)      // 8000 4-class chunks
#define NQH (NQ / 2)       // 4000 chunks per column half (K1)
#define NF1 (NQH / NT)     // 7 full iterations (K1)
#define TL1 (NQH - NF1*NT) // 416 tail threads (K1)
#define NFULL (NQ / NT)    // 15 full iterations (K2/mono)
#define TAILN (NQ - NFULL*NT) // 320 (wave-aligned tail)
#define WS_BYTES (GRID2 * 2 * 14 * sizeof(float))   // 57344

#define L2E 1.4426950408889634f
#define LN2 0.6931471805599453f

typedef float v2f __attribute__((ext_vector_type(2)));

__device__ __forceinline__ v2f splat2(float s) { v2f v; v.x = s; v.y = s; return v; }

__device__ __forceinline__ float wave_red_sum(float v) {
    #pragma unroll
    for (int o = 32; o > 0; o >>= 1) v += __shfl_down(v, o, 64);
    return v;
}

// Round-10 = round-9 (two-kernel split) resubmitted after an infra failure
// ("container failed twice", no dispatch record). Only kernel-side risk we
// can't exclude: d_ws < 57344B -> OOB ws writes. Fix: kernel_launch guards
// on ws_size and falls back to the proven r6 monolithic kernel (52.1us).
// Split rationale (r9): r6's binding constraint is 16 waves/CU, grid-capped;
// pass-1 uses NO LDS pool since r6 -> own kernel at 32 waves/CU via
// column-split x2 (L2 traffic invariant; partials -> ws, fixed-order sums).
// Rules bank: budget<64-VGPR shapes spill (r3/r4); NT=1024 regresses (r7);
// LDS unsafeAtomicAdd -> FLAT atomics 5x (r1); micro-sched neutral (r5/r8).

// ================= Kernel 1: pass-1 moments, column half ==================
__global__ __launch_bounds__(NT, 4) void akl_p1(
    const float* __restrict__ h1, const float* __restrict__ e1,
    const float* __restrict__ h3, const float* __restrict__ e3,
    float* __restrict__ ws)
{
    const int tid  = threadIdx.x;
    const int lane = tid & 63, wid = tid >> 6;   // 8 waves
    const int pair = blockIdx.x >> 1, half = blockIdx.x & 1;
    const int row0 = pair * R;

    __shared__ float red[112];     // 8 waves x 14

    float a1L[R], b1L[R], a2L[R], b2L[R], mh1L[R], mh2L[R], icwC[R], c0C[R];
    #pragma unroll
    for (int r = 0; r < R; r++) {
        a1L[r] = h1[2*(row0+r)] * L2E; b1L[r] = h1[2*(row0+r)+1] * L2E;
        a2L[r] = h3[2*(row0+r)] * L2E; b2L[r] = h3[2*(row0+r)+1] * L2E;
        mh1L[r] = 6.0f * (fabsf(a1L[r]) + fabsf(b1L[r]));   // safe shift
        mh2L[r] = 6.0f * (fabsf(a2L[r]) + fabsf(b2L[r]));
        float sp = fmaxf(sqrtf(a2L[r]*a2L[r] + b2L[r]*b2L[r]), 1e-6f);
        icwC[r] = 1.0f / (1.35f * sp);           // 4 cells over [-0.5s, +4.9s]
        c0C[r] = 0.5f/1.35f + mh2L[r]*icwC[r];   // cb=(int)(l2s*icwC + c0C)
    }

    const float4* __restrict__ E1 = (const float4*)e1;
    const float4* __restrict__ E3 = (const float4*)e3;

    const int base = half * NQH;
    const int cnt = NF1 + ((tid < TL1) ? 1 : 0);

    v2f U1v[R], S1v[R], S2v[R], q0v[R], q1v[R], q2v[R], q3v[R];
    #pragma unroll
    for (int r = 0; r < R; r++) {
        U1v[r] = splat2(0.f); S1v[r] = splat2(0.f); S2v[r] = splat2(0.f);
        q0v[r] = splat2(0.f); q1v[r] = splat2(0.f);
        q2v[r] = splat2(0.f); q3v[r] = splat2(0.f);
    }

    auto body1 = [&](float4 A0, float4 A1, float4 B0, float4 B1) {
        #pragma unroll
        for (int p = 0; p < 2; p++) {
            float4 A = p ? A1 : A0, B = p ? B1 : B0;
            v2f X1; X1.x = A.x; X1.y = A.z;
            v2f Y1; Y1.x = A.y; Y1.y = A.w;
            v2f X3; X3.x = B.x; X3.y = B.z;
            v2f Y3; Y3.x = B.y; Y3.y = B.w;
            #pragma unroll
            for (int r = 0; r < R; r++) {
                const v2f a1v = splat2(a1L[r]), b1v = splat2(b1L[r]);
                const v2f a2v = splat2(a2L[r]), b2v = splat2(b2L[r]);
                const v2f m1v = splat2(-mh1L[r]), m2v = splat2(-mh2L[r]);
                const v2f icv = splat2(icwC[r]), c0v = splat2(c0C[r]);
                v2f l1 = a1v*X1 + (b1v*Y1 + m1v);     // pk_fma
                v2f l2 = a2v*X3 + (b2v*Y3 + m2v);
                v2f e1v; e1v.x = __builtin_amdgcn_exp2f(l1.x);
                         e1v.y = __builtin_amdgcn_exp2f(l1.y);
                v2f e2v; e2v.x = __builtin_amdgcn_exp2f(l2.x);
                         e2v.y = __builtin_amdgcn_exp2f(l2.y);
                v2f dp = l2 - l1;                     // corrected post-pass
                U1v[r] += e1v;
                S1v[r] += e1v * dp;
                S2v[r] += e2v * dp;
                v2f t = l2*icv + c0v;
                v2f bfv;                               // bin idx in [0,3], float
                bfv.x = truncf(fminf(fmaxf(t.x, 0.f), 3.f));  // med3+trunc
                bfv.y = truncf(fminf(fmaxf(t.y, 0.f), 3.f));
                v2f bf2 = bfv*bfv, bf3 = bf2*bfv;
                q0v[r] += e2v;                         // == U2 contribution
                q1v[r] += e2v * bfv;
                q2v[r] += e2v * bf2;
                q3v[r] += e2v * bf3;
            }
        }
    };

    {
        float4 cA0 = E1[2*(base+tid)], cA1 = E1[2*(base+tid)+1];
        float4 cB0 = E3[2*(base+tid)], cB1 = E3[2*(base+tid)+1];
        #pragma unroll 1
        for (int it = 0; it < cnt; ++it) {
            const int jn = (it+1 < cnt) ? (base + (it+1)*NT + tid)
                                        : (base + tid);          // clamped
            float4 nA0 = E1[2*jn], nA1 = E1[2*jn+1];
            float4 nB0 = E3[2*jn], nB1 = E3[2*jn+1];
            body1(cA0, cA1, cB0, cB1);
            cA0 = nA0; cA1 = nA1; cB0 = nB0; cB1 = nB1;
        }
    }

    #pragma unroll
    for (int r = 0; r < R; r++) {
        float v0 = wave_red_sum(U1v[r].x + U1v[r].y);
        float v1 = wave_red_sum(S1v[r].x + S1v[r].y);
        float v2 = wave_red_sum(S2v[r].x + S2v[r].y);
        float v3 = wave_red_sum(q0v[r].x + q0v[r].y);
        float v4 = wave_red_sum(q1v[r].x + q1v[r].y);
        float v5 = wave_red_sum(q2v[r].x + q2v[r].y);
        float v6 = wave_red_sum(q3v[r].x + q3v[r].y);
        if (lane == 0) {
            red[wid*14 + r*7 + 0] = v0; red[wid*14 + r*7 + 1] = v1;
            red[wid*14 + r*7 + 2] = v2; red[wid*14 + r*7 + 3] = v3;
            red[wid*14 + r*7 + 4] = v4; red[wid*14 + r*7 + 5] = v5;
            red[wid*14 + r*7 + 6] = v6;
        }
    }
    __syncthreads();

    if (tid < 14) {                       // fixed-order block reduce -> ws
        int r = tid / 7, k = tid % 7;
        float s = 0.f;
        #pragma unroll
        for (int w = 0; w < 8; w++) s += red[w*14 + r*7 + k];
        ws[(pair*2 + half)*14 + r*7 + k] = s;
    }
}

// ========= Kernel 2: row params (from ws) + pass-2 fine partition =========
__global__ __launch_bounds__(NT, 4) void akl_p2(
    const float* __restrict__ h1, const float* __restrict__ e1,
    const float* __restrict__ h3, const float* __restrict__ e3,
    const float* __restrict__ ws, float* __restrict__ out)
{
    const int tid  = threadIdx.x;
    const int lane = tid & 63, wid = tid >> 6;   // 8 waves
    const int pair = blockIdx.x;
    const int row0 = pair * R;

    __shared__ float pool[16384];  // 64 KB fine pool:
    // fine e2 row r: base r*4096; fine gap row r: base (2+r)*4096
    __shared__ float red[32];
    __shared__ float shFP[R*KF], shFG[R*KF];
    __shared__ float shA[R][7];    // c, thr, fkl, rkl, icwF, c0Fs, Spre

    float a1L[R], b1L[R], a2L[R], b2L[R], mh1L[R], mh2L[R];
    #pragma unroll
    for (int r = 0; r < R; r++) {
        a1L[r] = h1[2*(row0+r)] * L2E; b1L[r] = h1[2*(row0+r)+1] * L2E;
        a2L[r] = h3[2*(row0+r)] * L2E; b2L[r] = h3[2*(row0+r)+1] * L2E;
        mh1L[r] = 6.0f * (fabsf(a1L[r]) + fabsf(b1L[r]));
        mh2L[r] = 6.0f * (fabsf(a2L[r]) + fabsf(b2L[r]));
    }

    // zero fine pool (vectorized)
    {
        float4* P4 = reinterpret_cast<float4*>(pool);
        float4 z; z.x = 0.f; z.y = 0.f; z.z = 0.f; z.w = 0.f;
        for (int i = tid; i < 4096; i += NT) P4[i] = z;
    }

    // ---- Row params + coarse crossing cell (one thread per row) ----
    if (tid < R) {
        const int r = tid;
        const float* W0 = ws + (pair*2 + 0)*14 + r*7;
        const float* W1 = ws + (pair*2 + 1)*14 + r*7;
        float U1s = W0[0] + W1[0];
        float S1s = W0[1] + W1[1];
        float S2s = W0[2] + W1[2];
        float Q0  = W0[3] + W1[3];
        float Q1  = W0[4] + W1[4];
        float Q2  = W0[5] + W1[5];
        float Q3  = W0[6] + W1[6];
        float U2s = Q0;
        // exact bin sums via inverse Vandermonde on nodes {0,1,2,3}
        float sb[KC];
        sb[0] = Q0 - (11.f*Q1 - 6.f*Q2 + Q3) * (1.f/6.f);
        sb[1] = (6.f*Q1 - 5.f*Q2 + Q3) * 0.5f;
        sb[2] = (4.f*Q2 - 3.f*Q1 - Q3) * 0.5f;
        sb[3] = (2.f*Q1 - 3.f*Q2 + Q3) * (1.f/6.f);
        float mh1r = r ? mh1L[1] : mh1L[0];
        float mh2r = r ? mh2L[1] : mh2L[0];
        float a2r = r ? a2L[1] : a2L[0];
        float b2r = r ? b2L[1] : b2L[0];
        float dmh = mh2r - mh1r;
        S1s += dmh * U1s;                        // exact shift correction
        S2s += dmh * U2s;
        float M1 = mh1r + __builtin_amdgcn_logf(U1s);
        float M2 = mh2r + __builtin_amdgcn_logf(U2s);
        float delta = M2 - M1;
        float thr = 0.5f * U2s;
        float S = 0.f; int bsel = KC-1;
        #pragma unroll
        for (int i = 0; i < KC; i++) {
            float m = sb[i];
            if (S + m >= thr) { bsel = i; break; }
            S += m;
        }
        float sp = fmaxf(sqrtf(a2r*a2r + b2r*b2r), 1e-6f);
        float wc  = 1.35f * sp;                  // coarse cell width
        float loS_s = fmaf((float)bsel, wc, -0.5f*sp) - mh2r;  // shifted space
        float icwF = (float)KF / wc;
        shA[r][0] = U2s / U1s;                   // c (gap scale fold)
        shA[r][1] = thr;
        shA[r][2] = LN2 * (S2s/U2s - delta);     // fkl
        shA[r][3] = LN2 * (delta - S1s/U1s);     // rkl
        shA[r][4] = icwF;
        shA[r][5] = -loS_s * icwF;               // c0Fs: t=l2s*icwF+c0Fs
        shA[r][6] = S;                           // Spre (unnorm prefix below cell)
    }
    __syncthreads();                                                   // B1

    const float4* __restrict__ E1 = (const float4*)e1;
    const float4* __restrict__ E3 = (const float4*)e3;
    const int cnt = NFULL + ((tid < TAILN) ? 1 : 0);

    float cR[R], icwFl[R], c0Fl[R];
    #pragma unroll
    for (int r = 0; r < R; r++) {
        cR[r] = shA[r][0]; icwFl[r] = shA[r][4]; c0Fl[r] = shA[r][5];
    }
    v2f gtv[R], Gpv[R];
    #pragma unroll
    for (int r = 0; r < R; r++) { gtv[r] = splat2(0.f); Gpv[r] = splat2(0.f); }

    auto body2 = [&](float4 A0, float4 A1, float4 B0, float4 B1) {
        #pragma unroll
        for (int p = 0; p < 2; p++) {
            float4 A = p ? A1 : A0, B = p ? B1 : B0;
            v2f X1; X1.x = A.x; X1.y = A.z;
            v2f Y1; Y1.x = A.y; Y1.y = A.w;
            v2f X3; X3.x = B.x; X3.y = B.z;
            v2f Y3; Y3.x = B.y; Y3.y = B.w;
            #pragma unroll
            for (int r = 0; r < R; r++) {
                const v2f a1v = splat2(a1L[r]), b1v = splat2(b1L[r]);
                const v2f a2v = splat2(a2L[r]), b2v = splat2(b2L[r]);
                const v2f m1v = splat2(-mh1L[r]), m2v = splat2(-mh2L[r]);
                const v2f cv = splat2(-cR[r]);
                const v2f icv = splat2(icwFl[r]), c0v = splat2(c0Fl[r]);
                float* HP = pool + r*4096;
                float* HG = pool + (2+r)*4096;
                v2f l1 = a1v*X1 + (b1v*Y1 + m1v);
                v2f l2 = a2v*X3 + (b2v*Y3 + m2v);
                v2f e1v; e1v.x = __builtin_amdgcn_exp2f(l1.x);
                         e1v.y = __builtin_amdgcn_exp2f(l1.y);
                v2f e2v; e2v.x = __builtin_amdgcn_exp2f(l2.x);
                         e2v.y = __builtin_amdgcn_exp2f(l2.y);
                v2f d = cv*e1v + e2v;                // e2 - c*e1 (pk_fma)
                v2f gap; gap.x = fabsf(d.x); gap.y = fabsf(d.y);
                gtv[r] += gap;
                v2f t = l2*icv + c0v;
                Gpv[r].x += (t.x < 0.f) ? gap.x : 0.f;
                Gpv[r].y += (t.y < 0.f) ? gap.y : 0.f;
                if (t.x >= 0.f && t.x < (float)KF) {   // ~1% of elements
                    int fb = (int)t.x;
                    HP[fb*NT + tid] += e2v.x;
                    HG[fb*NT + tid] += gap.x;
                }
                if (t.y >= 0.f && t.y < (float)KF) {
                    int fb = (int)t.y;
                    HP[fb*NT + tid] += e2v.y;
                    HG[fb*NT + tid] += gap.y;
                }
            }
        }
    };

    {
        float4 cA0 = E1[2*tid], cA1 = E1[2*tid+1];
        float4 cB0 = E3[2*tid], cB1 = E3[2*tid+1];
        #pragma unroll 1
        for (int it = 0; it < cnt; ++it) {
            const int jn = (it+1 < cnt) ? ((it+1)*NT + tid) : tid;  // clamped
            float4 nA0 = E1[2*jn], nA1 = E1[2*jn+1];
            float4 nB0 = E3[2*jn], nB1 = E3[2*jn+1];
            body2(cA0, cA1, cB0, cB1);
            cA0 = nA0; cA1 = nA1; cB0 = nB0; cB1 = nB1;
        }
    }

    #pragma unroll
    for (int r = 0; r < R; r++) {
        float a = wave_red_sum(gtv[r].x + gtv[r].y);
        float b = wave_red_sum(Gpv[r].x + Gpv[r].y);
        if (lane == 0) { red[wid*4 + r*2 + 0] = a; red[wid*4 + r*2 + 1] = b; }
    }
    __syncthreads();                                                   // B2

    // ---- Reduce fine histograms: 32 groups x 16 lanes ----
    {
        int grp = tid >> 4, l16 = tid & 15;      // 32 groups
        int isG = grp >> 4;                      // 0: P, 1: G
        int r = (grp >> 3) & 1, b = grp & 7;
        const float* H = pool + (isG*2 + r)*4096 + b*512;
        float s = 0.f;
        #pragma unroll
        for (int t = 0; t < NT/16; t++) s += H[l16 + t*16];
        #pragma unroll
        for (int o = 8; o > 0; o >>= 1) s += __shfl_down(s, o, 64);
        if (l16 == 0) {
            if (isG) shFG[r*KF + b] = s; else shFP[r*KF + b] = s;
        }
    }
    __syncthreads();                                                   // B3

    // ---- Walk fine bins, secant-interpolate 0.5 crossing, output ----
    if (tid < R) {
        const int r = tid;
        float gts = 0, Gp = 0;
        for (int w = 0; w < 8; w++) {
            gts += red[w*4 + r*2 + 0];
            Gp  += red[w*4 + r*2 + 1];
        }
        float thr = shA[r][1], fkl = shA[r][2], rkl = shA[r][3];
        float S = shA[r][6], G = Gp;
        bool done = false;
        #pragma unroll
        for (int i = 0; i < KF; i++) {
            if (!done) {
                float p = shFP[r*KF + i], g = shFG[r*KF + i];
                float ns = S + p;
                if (ns >= thr) {
                    float f = (thr - S) / fmaxf(p, 1e-30f);
                    f = fminf(fmaxf(f, 0.f), 1.f);
                    G += f * g;
                    done = true;
                } else { S = ns; G += g; }
            }
        }
        float gl = G;                    // g_tail (unnormalized: scale cancels)
        float gh = gts - gl;             // g_head
        float akl = (gh*fkl + gl*rkl) / gts;
        unsafeAtomicAdd(out, akl * (1.0f/(float)DNUM));
    }
}

// ============ Fallback: proven r6 monolithic kernel (52.1us) ==============
__global__ __launch_bounds__(NT, 4) void akl_rows_mono(
    const float* __restrict__ h1, const float* __restrict__ e1,
    const float* __restrict__ h3, const float* __restrict__ e3,
    float* __restrict__ out)
{
    const int tid  = threadIdx.x;
    const int lane = tid & 63, wid = tid >> 6;   // 8 waves
    const int row0 = blockIdx.x * R;

    __shared__ float pool[16384];
    __shared__ float red[112];
    __shared__ float shFP[R*KF], shFG[R*KF];
    __shared__ float shA[R][7];

    float a1L[R], b1L[R], a2L[R], b2L[R], mh1L[R], mh2L[R], icwC[R], c0C[R];
    #pragma unroll
    for (int r = 0; r < R; r++) {
        a1L[r] = h1[2*(row0+r)] * L2E; b1L[r] = h1[2*(row0+r)+1] * L2E;
        a2L[r] = h3[2*(row0+r)] * L2E; b2L[r] = h3[2*(row0+r)+1] * L2E;
        mh1L[r] = 6.0f * (fabsf(a1L[r]) + fabsf(b1L[r]));
        mh2L[r] = 6.0f * (fabsf(a2L[r]) + fabsf(b2L[r]));
        float sp = fmaxf(sqrtf(a2L[r]*a2L[r] + b2L[r]*b2L[r]), 1e-6f);
        icwC[r] = 1.0f / (1.35f * sp);
        c0C[r] = 0.5f/1.35f + mh2L[r]*icwC[r];
    }

    const float4* __restrict__ E1 = (const float4*)e1;
    const float4* __restrict__ E3 = (const float4*)e3;
    const int cnt = NFULL + ((tid < TAILN) ? 1 : 0);

    v2f U1v[R], S1v[R], S2v[R], q0v[R], q1v[R], q2v[R], q3v[R];
    #pragma unroll
    for (int r = 0; r < R; r++) {
        U1v[r] = splat2(0.f); S1v[r] = splat2(0.f); S2v[r] = splat2(0.f);
        q0v[r] = splat2(0.f); q1v[r] = splat2(0.f);
        q2v[r] = splat2(0.f); q3v[r] = splat2(0.f);
    }

    auto body1 = [&](float4 A0, float4 A1, float4 B0, float4 B1) {
        #pragma unroll
        for (int p = 0; p < 2; p++) {
            float4 A = p ? A1 : A0, B = p ? B1 : B0;
            v2f X1; X1.x = A.x; X1.y = A.z;
            v2f Y1; Y1.x = A.y; Y1.y = A.w;
            v2f X3; X3.x = B.x; X3.y = B.z;
            v2f Y3; Y3.x = B.y; Y3.y = B.w;
            #pragma unroll
            for (int r = 0; r < R; r++) {
                const v2f a1v = splat2(a1L[r]), b1v = splat2(b1L[r]);
                const v2f a2v = splat2(a2L[r]), b2v = splat2(b2L[r]);
                const v2f m1v = splat2(-mh1L[r]), m2v = splat2(-mh2L[r]);
                const v2f icv = splat2(icwC[r]), c0v = splat2(c0C[r]);
                v2f l1 = a1v*X1 + (b1v*Y1 + m1v);
                v2f l2 = a2v*X3 + (b2v*Y3 + m2v);
                v2f e1v; e1v.x = __builtin_amdgcn_exp2f(l1.x);
                         e1v.y = __builtin_amdgcn_exp2f(l1.y);
                v2f e2v; e2v.x = __builtin_amdgcn_exp2f(l2.x);
                         e2v.y = __builtin_amdgcn_exp2f(l2.y);
                v2f dp = l2 - l1;
                U1v[r] += e1v;
                S1v[r] += e1v * dp;
                S2v[r] += e2v * dp;
                v2f t = l2*icv + c0v;
                v2f bfv;
                bfv.x = truncf(fminf(fmaxf(t.x, 0.f), 3.f));
                bfv.y = truncf(fminf(fmaxf(t.y, 0.f), 3.f));
                v2f bf2 = bfv*bfv, bf3 = bf2*bfv;
                q0v[r] += e2v;
                q1v[r] += e2v * bfv;
                q2v[r] += e2v * bf2;
                q3v[r] += e2v * bf3;
            }
        }
    };

    {
        float4 cA0 = E1[2*tid], cA1 = E1[2*tid+1];
        float4 cB0 = E3[2*tid], cB1 = E3[2*tid+1];
        #pragma unroll 1
        for (int it = 0; it < cnt; ++it) {
            const int jn = (it+1 < cnt) ? ((it+1)*NT + tid) : tid;
            float4 nA0 = E1[2*jn], nA1 = E1[2*jn+1];
            float4 nB0 = E3[2*jn], nB1 = E3[2*jn+1];
            body1(cA0, cA1, cB0, cB1);
            cA0 = nA0; cA1 = nA1; cB0 = nB0; cB1 = nB1;
        }
    }

    #pragma unroll
    for (int r = 0; r < R; r++) {
        float v0 = wave_red_sum(U1v[r].x + U1v[r].y);
        float v1 = wave_red_sum(S1v[r].x + S1v[r].y);
        float v2 = wave_red_sum(S2v[r].x + S2v[r].y);
        float v3 = wave_red_sum(q0v[r].x + q0v[r].y);
        float v4 = wave_red_sum(q1v[r].x + q1v[r].y);
        float v5 = wave_red_sum(q2v[r].x + q2v[r].y);
        float v6 = wave_red_sum(q3v[r].x + q3v[r].y);
        if (lane == 0) {
            red[wid*14 + r*7 + 0] = v0; red[wid*14 + r*7 + 1] = v1;
            red[wid*14 + r*7 + 2] = v2; red[wid*14 + r*7 + 3] = v3;
            red[wid*14 + r*7 + 4] = v4; red[wid*14 + r*7 + 5] = v5;
            red[wid*14 + r*7 + 6] = v6;
        }
    }
    {
        float4* P4 = reinterpret_cast<float4*>(pool);
        float4 z; z.x = 0.f; z.y = 0.f; z.z = 0.f; z.w = 0.f;
        for (int i = tid; i < 4096; i += NT) P4[i] = z;
    }
    __syncthreads();

    if (tid < R) {
        const int r = tid;
        float U1s = 0, S1s = 0, S2s = 0, Q0 = 0, Q1 = 0, Q2 = 0, Q3 = 0;
        for (int w = 0; w < 8; w++) {
            U1s += red[w*14 + r*7 + 0];
            S1s += red[w*14 + r*7 + 1];
            S2s += red[w*14 + r*7 + 2];
            Q0  += red[w*14 + r*7 + 3];
            Q1  += red[w*14 + r*7 + 4];
            Q2  += red[w*14 + r*7 + 5];
            Q3  += red[w*14 + r*7 + 6];
        }
        float U2s = Q0;
        float sb[KC];
        sb[0] = Q0 - (11.f*Q1 - 6.f*Q2 + Q3) * (1.f/6.f);
        sb[1] = (6.f*Q1 - 5.f*Q2 + Q3) * 0.5f;
        sb[2] = (4.f*Q2 - 3.f*Q1 - Q3) * 0.5f;
        sb[3] = (2.f*Q1 - 3.f*Q2 + Q3) * (1.f/6.f);
        float mh1r = r ? mh1L[1] : mh1L[0];
        float mh2r = r ? mh2L[1] : mh2L[0];
        float a2r = r ? a2L[1] : a2L[0];
        float b2r = r ? b2L[1] : b2L[0];
        float dmh = mh2r - mh1r;
        S1s += dmh * U1s;
        S2s += dmh * U2s;
        float M1 = mh1r + __builtin_amdgcn_logf(U1s);
        float M2 = mh2r + __builtin_amdgcn_logf(U2s);
        float delta = M2 - M1;
        float thr = 0.5f * U2s;
        float S = 0.f; int bsel = KC-1;
        #pragma unroll
        for (int i = 0; i < KC; i++) {
            float m = sb[i];
            if (S + m >= thr) { bsel = i; break; }
            S += m;
        }
        float sp = fmaxf(sqrtf(a2r*a2r + b2r*b2r), 1e-6f);
        float wc  = 1.35f * sp;
        float loS_s = fmaf((float)bsel, wc, -0.5f*sp) - mh2r;
        float icwF = (float)KF / wc;
        shA[r][0] = U2s / U1s;
        shA[r][1] = thr;
        shA[r][2] = LN2 * (S2s/U2s - delta);
        shA[r][3] = LN2 * (delta - S1s/U1s);
        shA[r][4] = icwF;
        shA[r][5] = -loS_s * icwF;
        shA[r][6] = S;
    }
    __syncthreads();

    float cR[R], icwFl[R], c0Fl[R];
    #pragma unroll
    for (int r = 0; r < R; r++) {
        cR[r] = shA[r][0]; icwFl[r] = shA[r][4]; c0Fl[r] = shA[r][5];
    }
    v2f gtv[R], Gpv[R];
    #pragma unroll
    for (int r = 0; r < R; r++) { gtv[r] = splat2(0.f); Gpv[r] = splat2(0.f); }

    auto body2 = [&](float4 A0, float4 A1, float4 B0, float4 B1) {
        #pragma unroll
        for (int p = 0; p < 2; p++) {
            float4 A = p ? A1 : A0, B = p ? B1 : B0;
            v2f X1; X1.x = A.x; X1.y = A.z;
            v2f Y1; Y1.x = A.y; Y1.y = A.w;
            v2f X3; X3.x = B.x; X3.y = B.z;
            v2f Y3; Y3.x = B.y; Y3.y = B.w;
            #pragma unroll
            for (int r = 0; r < R; r++) {
                const v2f a1v = splat2(a1L[r]), b1v = splat2(b1L[r]);
                const v2f a2v = splat2(a2L[r]), b2v = splat2(b2L[r]);
                const v2f m1v = splat2(-mh1L[r]), m2v = splat2(-mh2L[r]);
                const v2f cv = splat2(-cR[r]);
                const v2f icv = splat2(icwFl[r]), c0v = splat2(c0Fl[r]);
                float* HP = pool + r*4096;
                float* HG = pool + (2+r)*4096;
                v2f l1 = a1v*X1 + (b1v*Y1 + m1v);
                v2f l2 = a2v*X3 + (b2v*Y3 + m2v);
                v2f e1v; e1v.x = __builtin_amdgcn_exp2f(l1.x);
                         e1v.y = __builtin_amdgcn_exp2f(l1.y);
                v2f e2v; e2v.x = __builtin_amdgcn_exp2f(l2.x);
                         e2v.y = __builtin_amdgcn_exp2f(l2.y);
                v2f d = cv*e1v + e2v;
                v2f gap; gap.x = fabsf(d.x); gap.y = fabsf(d.y);
                gtv[r] += gap;
                v2f t = l2*icv + c0v;
                Gpv[r].x += (t.x < 0.f) ? gap.x : 0.f;
                Gpv[r].y += (t.y < 0.f) ? gap.y : 0.f;
                if (t.x >= 0.f && t.x < (float)KF) {
                    int fb = (int)t.x;
                    HP[fb*NT + tid] += e2v.x;
                    HG[fb*NT + tid] += gap.x;
                }
                if (t.y >= 0.f && t.y < (float)KF) {
                    int fb = (int)t.y;
                    HP[fb*NT + tid] += e2v.y;
                    HG[fb*NT + tid] += gap.y;
                }
            }
        }
    };

    {
        float4 cA0 = E1[2*tid], cA1 = E1[2*tid+1];
        float4 cB0 = E3[2*tid], cB1 = E3[2*tid+1];
        #pragma unroll 1
        for (int it = 0; it < cnt; ++it) {
            const int jn = (it+1 < cnt) ? ((it+1)*NT + tid) : tid;
            float4 nA0 = E1[2*jn], nA1 = E1[2*jn+1];
            float4 nB0 = E3[2*jn], nB1 = E3[2*jn+1];
            body2(cA0, cA1, cB0, cB1);
            cA0 = nA0; cA1 = nA1; cB0 = nB0; cB1 = nB1;
        }
    }

    #pragma unroll
    for (int r = 0; r < R; r++) {
        float a = wave_red_sum(gtv[r].x + gtv[r].y);
        float b = wave_red_sum(Gpv[r].x + Gpv[r].y);
        if (lane == 0) { red[wid*4 + r*2 + 0] = a; red[wid*4 + r*2 + 1] = b; }
    }
    __syncthreads();

    {
        int grp = tid >> 4, l16 = tid & 15;
        int isG = grp >> 4;
        int r = (grp >> 3) & 1, b = grp & 7;
        const float* H = pool + (isG*2 + r)*4096 + b*512;
        float s = 0.f;
        #pragma unroll
        for (int t = 0; t < NT/16; t++) s += H[l16 + t*16];
        #pragma unroll
        for (int o = 8; o > 0; o >>= 1) s += __shfl_down(s, o, 64);
        if (l16 == 0) {
            if (isG) shFG[r*KF + b] = s; else shFP[r*KF + b] = s;
        }
    }
    __syncthreads();

    if (tid < R) {
        const int r = tid;
        float gts = 0, Gp = 0;
        for (int w = 0; w < 8; w++) {
            gts += red[w*4 + r*2 + 0];
            Gp  += red[w*4 + r*2 + 1];
        }
        float thr = shA[r][1], fkl = shA[r][2], rkl = shA[r][3];
        float S = shA[r][6], G = Gp;
        bool done = false;
        #pragma unroll
        for (int i = 0; i < KF; i++) {
            if (!done) {
                float p = shFP[r*KF + i], g = shFG[r*KF + i];
                float ns = S + p;
                if (ns >= thr) {
                    float f = (thr - S) / fmaxf(p, 1e-30f);
                    f = fminf(fmaxf(f, 0.f), 1.f);
                    G += f * g;
                    done = true;
                } else { S = ns; G += g; }
            }
        }
        float gl = G;
        float gh = gts - gl;
        float akl = (gh*fkl + gl*rkl) / gts;
        unsafeAtomicAdd(out, akl * (1.0f/(float)DNUM));
    }
}

extern "C" void kernel_launch(void* const* d_in, const int* in_sizes, int n_in,
                              void* d_out, int out_size, void* d_ws, size_t ws_size,
                              hipStream_t stream) {
    const float* h1 = (const float*)d_in[0];
    const float* e1 = (const float*)d_in[1];
    const float* h3 = (const float*)d_in[2];
    const float* e3 = (const float*)d_in[3];
    hipMemsetAsync(d_out, 0, sizeof(float), stream);   // capture-safe
    if (d_ws != nullptr && ws_size >= WS_BYTES) {
        float* ws = (float*)d_ws;              // 512 pairs x 2 halves x 14 floats
        akl_p1<<<GRID1, NT, 0, stream>>>(h1, e1, h3, e3, ws);
        akl_p2<<<GRID2, NT, 0, stream>>>(h1, e1, h3, e3, ws, (float*)d_out);
    } else {
        akl_rows_mono<<<GRID2, NT, 0, stream>>>(h1, e1, h3, e3, (float*)d_out);
    }
}

// Round 11
// 106.709 us; speedup vs baseline: 1.0187x; 1.0187x over previous
//
#include <hip/hip_runtime.h>
#include <math.h>

#define DNUM 1024
#define CNUM 32000
#define NT 512             // 8 waves/block
#define R 2                // rows per block
#define GRID (DNUM / R)    // 512 blocks -> grid-capped 16 waves/CU
#define KC 4               // coarse bins (1.35 sigma each), span [-0.5s, +4.9s]
#define KF 8               // fine bins   (0.169 sigma each)
#define NQ (CNUM / 4)      // 8000 4-class chunks
#define NFULL (NQ / NT)    // 15 full iterations
#define TAILN (NQ - NFULL*NT) // 320 (wave-aligned tail)

#define L2E 1.4426950408889634f
#define LN2 0.6931471805599453f

typedef float v2f __attribute__((ext_vector_type(2)));

__device__ __forceinline__ v2f splat2(float s) { v2f v; v.x = s; v.y = s; return v; }

__device__ __forceinline__ float wave_red_sum(float v) {
    #pragma unroll
    for (int o = 32; o > 0; o >>= 1) v += __shfl_down(v, o, 64);
    return v;
}

// FINAL: exact revert to round-6, the session's best measured kernel
// (52.1us dispatch / 106.8us bench; VALU ~60%, VGPR 64, no spill).
// Structure: R=2 rows/block, NT=512, bounds(512,4); pass-1 entirely in
// registers (bin-moments q_k = sum(e2*b^k), exact bin sums via inverse
// Vandermonde on {0,1,2,3}); register prefetch of next chunk in both
// streaming loops; pass-2 fine histogram in a 64KB LDS pool with
// per-thread-private slots (plain +=).
// Session rules bank (what NOT to do, all measured):
//  - launch_bounds budget < 64 VGPR (min-waves>=8 or NT=1024 w/ 8) =>
//    allocator clamp -> scratch spill -> 2-4x regression (r3/r4).
//  - unsafeAtomicAdd on LDS lowers to FLAT atomics -> 5x regression (r1).
//  - NT=1024 16-wave blocks: barrier convoy + LDS edge -> +6us (r7).
//  - R=1 (occupancy 2x, loads 2x): +5us (r2).
//  - Two-kernel split (pass1 @32 waves/CU): neutral, launch overhead
//    cancels the gain (r9/r10).
//  - Micro-scheduling (affine peel, unpack hoist): neutral (r8).
// Ceiling: VALU-issue/latency equilibrium at 16 waves/CU, pinned by the
// triangle {VGPR<=64 body, 64KB pass-2 pool => 2 blocks/CU, grid=DNUM/R}.
__global__ __launch_bounds__(NT, 4) void akl_rows(
    const float* __restrict__ h1, const float* __restrict__ e1,
    const float* __restrict__ h3, const float* __restrict__ e3,
    float* __restrict__ out)
{
    const int tid  = threadIdx.x;
    const int lane = tid & 63, wid = tid >> 6;   // 8 waves
    const int row0 = blockIdx.x * R;

    __shared__ float pool[16384];  // 64 KB, pass-2 only:
    // fine e2 row r: base r*4096; fine gap row r: base (2+r)*4096
    __shared__ float red[112];     // pass1: 8 waves x (R*7); pass2 reuses 32
    __shared__ float shFP[R*KF], shFG[R*KF];
    __shared__ float shA[R][7];    // c, thr, fkl, rkl, icwF, c0Fs, Spre

    // Per-row coefficients, log2 domain
    float a1L[R], b1L[R], a2L[R], b2L[R], mh1L[R], mh2L[R], icwC[R], c0C[R];
    #pragma unroll
    for (int r = 0; r < R; r++) {
        a1L[r] = h1[2*(row0+r)] * L2E; b1L[r] = h1[2*(row0+r)+1] * L2E;
        a2L[r] = h3[2*(row0+r)] * L2E; b2L[r] = h3[2*(row0+r)+1] * L2E;
        mh1L[r] = 6.0f * (fabsf(a1L[r]) + fabsf(b1L[r]));   // safe shift
        mh2L[r] = 6.0f * (fabsf(a2L[r]) + fabsf(b2L[r]));
        float sp = fmaxf(sqrtf(a2L[r]*a2L[r] + b2L[r]*b2L[r]), 1e-6f);
        icwC[r] = 1.0f / (1.35f * sp);           // 4 cells over [-0.5s, +4.9s]
        c0C[r] = 0.5f/1.35f + mh2L[r]*icwC[r];   // cb=(int)(l2s*icwC + c0C)
    }

    const float4* __restrict__ E1 = (const float4*)e1;
    const float4* __restrict__ E3 = (const float4*)e3;

    // tail: TAILN=320 is wave-aligned -> no intra-wave divergence
    const int cnt = NFULL + ((tid < TAILN) ? 1 : 0);

    // ===== Pass 1: moments + coarse bin-moments (all-register) =====
    v2f U1v[R], S1v[R], S2v[R], q0v[R], q1v[R], q2v[R], q3v[R];
    #pragma unroll
    for (int r = 0; r < R; r++) {
        U1v[r] = splat2(0.f); S1v[r] = splat2(0.f); S2v[r] = splat2(0.f);
        q0v[r] = splat2(0.f); q1v[r] = splat2(0.f);
        q2v[r] = splat2(0.f); q3v[r] = splat2(0.f);
    }

    auto body1 = [&](float4 A0, float4 A1, float4 B0, float4 B1) {
        #pragma unroll
        for (int r = 0; r < R; r++) {
            const v2f a1v = splat2(a1L[r]), b1v = splat2(b1L[r]);
            const v2f a2v = splat2(a2L[r]), b2v = splat2(b2L[r]);
            const v2f m1v = splat2(-mh1L[r]), m2v = splat2(-mh2L[r]);
            const v2f icv = splat2(icwC[r]), c0v = splat2(c0C[r]);
            #pragma unroll
            for (int p = 0; p < 2; p++) {
                float4 A = p ? A1 : A0, B = p ? B1 : B0;
                v2f X1; X1.x = A.x; X1.y = A.z;
                v2f Y1; Y1.x = A.y; Y1.y = A.w;
                v2f X3; X3.x = B.x; X3.y = B.z;
                v2f Y3; Y3.x = B.y; Y3.y = B.w;
                v2f l1 = a1v*X1 + (b1v*Y1 + m1v);     // pk_fma
                v2f l2 = a2v*X3 + (b2v*Y3 + m2v);
                v2f e1v; e1v.x = __builtin_amdgcn_exp2f(l1.x);
                         e1v.y = __builtin_amdgcn_exp2f(l1.y);
                v2f e2v; e2v.x = __builtin_amdgcn_exp2f(l2.x);
                         e2v.y = __builtin_amdgcn_exp2f(l2.y);
                v2f dp = l2 - l1;                     // corrected post-pass
                U1v[r] += e1v;
                S1v[r] += e1v * dp;
                S2v[r] += e2v * dp;
                v2f t = l2*icv + c0v;
                v2f bfv;                               // bin idx in [0,3], float
                bfv.x = truncf(fminf(fmaxf(t.x, 0.f), 3.f));  // med3+trunc
                bfv.y = truncf(fminf(fmaxf(t.y, 0.f), 3.f));
                v2f bf2 = bfv*bfv, bf3 = bf2*bfv;
                q0v[r] += e2v;                         // == U2 contribution
                q1v[r] += e2v * bfv;
                q2v[r] += e2v * bf2;
                q3v[r] += e2v * bf3;
            }
        }
    };

    {
        float4 cA0 = E1[2*tid], cA1 = E1[2*tid+1];
        float4 cB0 = E3[2*tid], cB1 = E3[2*tid+1];
        #pragma unroll 1
        for (int it = 0; it < cnt; ++it) {
            const int jn = (it+1 < cnt) ? ((it+1)*NT + tid) : tid;  // clamped
            float4 nA0 = E1[2*jn], nA1 = E1[2*jn+1];
            float4 nB0 = E3[2*jn], nB1 = E3[2*jn+1];
            body1(cA0, cA1, cB0, cB1);
            cA0 = nA0; cA1 = nA1; cB0 = nB0; cB1 = nB1;
        }
    }

    #pragma unroll
    for (int r = 0; r < R; r++) {
        float v0 = wave_red_sum(U1v[r].x + U1v[r].y);
        float v1 = wave_red_sum(S1v[r].x + S1v[r].y);
        float v2 = wave_red_sum(S2v[r].x + S2v[r].y);
        float v3 = wave_red_sum(q0v[r].x + q0v[r].y);
        float v4 = wave_red_sum(q1v[r].x + q1v[r].y);
        float v5 = wave_red_sum(q2v[r].x + q2v[r].y);
        float v6 = wave_red_sum(q3v[r].x + q3v[r].y);
        if (lane == 0) {
            red[wid*14 + r*7 + 0] = v0; red[wid*14 + r*7 + 1] = v1;
            red[wid*14 + r*7 + 2] = v2; red[wid*14 + r*7 + 3] = v3;
            red[wid*14 + r*7 + 4] = v4; red[wid*14 + r*7 + 5] = v5;
            red[wid*14 + r*7 + 6] = v6;
        }
    }
    // zero pool for the fine pass (pass 1 never touches it), vectorized
    {
        float4* P4 = reinterpret_cast<float4*>(pool);
        float4 z; z.x = 0.f; z.y = 0.f; z.z = 0.f; z.w = 0.f;
        for (int i = tid; i < 4096; i += NT) P4[i] = z;
    }
    __syncthreads();                                                   // B1

    // ---- Row params + coarse crossing cell (one thread per row) ----
    if (tid < R) {
        const int r = tid;
        float U1s = 0, S1s = 0, S2s = 0, Q0 = 0, Q1 = 0, Q2 = 0, Q3 = 0;
        for (int w = 0; w < 8; w++) {
            U1s += red[w*14 + r*7 + 0];
            S1s += red[w*14 + r*7 + 1];
            S2s += red[w*14 + r*7 + 2];
            Q0  += red[w*14 + r*7 + 3];
            Q1  += red[w*14 + r*7 + 4];
            Q2  += red[w*14 + r*7 + 5];
            Q3  += red[w*14 + r*7 + 6];
        }
        float U2s = Q0;
        // exact bin sums via inverse Vandermonde on nodes {0,1,2,3}
        float sb[KC];
        sb[0] = Q0 - (11.f*Q1 - 6.f*Q2 + Q3) * (1.f/6.f);
        sb[1] = (6.f*Q1 - 5.f*Q2 + Q3) * 0.5f;
        sb[2] = (4.f*Q2 - 3.f*Q1 - Q3) * 0.5f;
        sb[3] = (2.f*Q1 - 3.f*Q2 + Q3) * (1.f/6.f);
        float mh1r = r ? mh1L[1] : mh1L[0];
        float mh2r = r ? mh2L[1] : mh2L[0];
        float a2r = r ? a2L[1] : a2L[0];
        float b2r = r ? b2L[1] : b2L[0];
        float dmh = mh2r - mh1r;
        S1s += dmh * U1s;                        // exact shift correction
        S2s += dmh * U2s;
        float M1 = mh1r + __builtin_amdgcn_logf(U1s);
        float M2 = mh2r + __builtin_amdgcn_logf(U2s);
        float delta = M2 - M1;
        float thr = 0.5f * U2s;
        float S = 0.f; int bsel = KC-1;
        #pragma unroll
        for (int i = 0; i < KC; i++) {
            float m = sb[i];
            if (S + m >= thr) { bsel = i; break; }
            S += m;
        }
        float sp = fmaxf(sqrtf(a2r*a2r + b2r*b2r), 1e-6f);
        float wc  = 1.35f * sp;                  // coarse cell width
        float loS_s = fmaf((float)bsel, wc, -0.5f*sp) - mh2r;  // shifted space
        float icwF = (float)KF / wc;
        shA[r][0] = U2s / U1s;                   // c (gap scale fold)
        shA[r][1] = thr;
        shA[r][2] = LN2 * (S2s/U2s - delta);     // fkl
        shA[r][3] = LN2 * (delta - S1s/U1s);     // rkl
        shA[r][4] = icwF;
        shA[r][5] = -loS_s * icwF;               // c0Fs: t=l2s*icwF+c0Fs
        shA[r][6] = S;                           // Spre (unnorm prefix below cell)
    }
    __syncthreads();                                                   // B2

    // ================= Pass 2: gap stats + fine partition ===================
    float cR[R], icwFl[R], c0Fl[R];
    #pragma unroll
    for (int r = 0; r < R; r++) {
        cR[r] = shA[r][0]; icwFl[r] = shA[r][4]; c0Fl[r] = shA[r][5];
    }
    v2f gtv[R], Gpv[R];
    #pragma unroll
    for (int r = 0; r < R; r++) { gtv[r] = splat2(0.f); Gpv[r] = splat2(0.f); }

    auto body2 = [&](float4 A0, float4 A1, float4 B0, float4 B1) {
        #pragma unroll
        for (int r = 0; r < R; r++) {
            const v2f a1v = splat2(a1L[r]), b1v = splat2(b1L[r]);
            const v2f a2v = splat2(a2L[r]), b2v = splat2(b2L[r]);
            const v2f m1v = splat2(-mh1L[r]), m2v = splat2(-mh2L[r]);
            const v2f cv = splat2(-cR[r]);
            const v2f icv = splat2(icwFl[r]), c0v = splat2(c0Fl[r]);
            float* HP = pool + r*4096;
            float* HG = pool + (2+r)*4096;
            #pragma unroll
            for (int p = 0; p < 2; p++) {
                float4 A = p ? A1 : A0, B = p ? B1 : B0;
                v2f X1; X1.x = A.x; X1.y = A.z;
                v2f Y1; Y1.x = A.y; Y1.y = A.w;
                v2f X3; X3.x = B.x; X3.y = B.z;
                v2f Y3; Y3.x = B.y; Y3.y = B.w;
                v2f l1 = a1v*X1 + (b1v*Y1 + m1v);
                v2f l2 = a2v*X3 + (b2v*Y3 + m2v);
                v2f e1v; e1v.x = __builtin_amdgcn_exp2f(l1.x);
                         e1v.y = __builtin_amdgcn_exp2f(l1.y);
                v2f e2v; e2v.x = __builtin_amdgcn_exp2f(l2.x);
                         e2v.y = __builtin_amdgcn_exp2f(l2.y);
                v2f d = cv*e1v + e2v;                // e2 - c*e1 (pk_fma)
                v2f gap; gap.x = fabsf(d.x); gap.y = fabsf(d.y);
                gtv[r] += gap;
                v2f t = l2*icv + c0v;
                Gpv[r].x += (t.x < 0.f) ? gap.x : 0.f;
                Gpv[r].y += (t.y < 0.f) ? gap.y : 0.f;
                if (t.x >= 0.f && t.x < (float)KF) {   // ~1% of elements
                    int fb = (int)t.x;
                    HP[fb*NT + tid] += e2v.x;
                    HG[fb*NT + tid] += gap.x;
                }
                if (t.y >= 0.f && t.y < (float)KF) {
                    int fb = (int)t.y;
                    HP[fb*NT + tid] += e2v.y;
                    HG[fb*NT + tid] += gap.y;
                }
            }
        }
    };

    {
        float4 cA0 = E1[2*tid], cA1 = E1[2*tid+1];
        float4 cB0 = E3[2*tid], cB1 = E3[2*tid+1];
        #pragma unroll 1
        for (int it = 0; it < cnt; ++it) {
            const int jn = (it+1 < cnt) ? ((it+1)*NT + tid) : tid;  // clamped
            float4 nA0 = E1[2*jn], nA1 = E1[2*jn+1];
            float4 nB0 = E3[2*jn], nB1 = E3[2*jn+1];
            body2(cA0, cA1, cB0, cB1);
            cA0 = nA0; cA1 = nA1; cB0 = nB0; cB1 = nB1;
        }
    }

    #pragma unroll
    for (int r = 0; r < R; r++) {
        float a = wave_red_sum(gtv[r].x + gtv[r].y);
        float b = wave_red_sum(Gpv[r].x + Gpv[r].y);
        if (lane == 0) { red[wid*4 + r*2 + 0] = a; red[wid*4 + r*2 + 1] = b; }
    }
    __syncthreads();                                                   // B3

    // ---- Reduce fine histograms: 32 groups x 16 lanes ----
    {
        int grp = tid >> 4, l16 = tid & 15;      // 32 groups
        int isG = grp >> 4;                      // 0: P, 1: G
        int r = (grp >> 3) & 1, b = grp & 7;
        const float* H = pool + (isG*2 + r)*4096 + b*512;
        float s = 0.f;
        #pragma unroll
        for (int t = 0; t < NT/16; t++) s += H[l16 + t*16];
        #pragma unroll
        for (int o = 8; o > 0; o >>= 1) s += __shfl_down(s, o, 64);
        if (l16 == 0) {
            if (isG) shFG[r*KF + b] = s; else shFP[r*KF + b] = s;
        }
    }
    __syncthreads();                                                   // B4

    // ---- Walk fine bins, secant-interpolate 0.5 crossing, output ----
    if (tid < R) {
        const int r = tid;
        float gts = 0, Gp = 0;
        for (int w = 0; w < 8; w++) {
            gts += red[w*4 + r*2 + 0];
            Gp  += red[w*4 + r*2 + 1];
        }
        float thr = shA[r][1], fkl = shA[r][2], rkl = shA[r][3];
        float S = shA[r][6], G = Gp;
        bool done = false;
        #pragma unroll
        for (int i = 0; i < KF; i++) {
            if (!done) {
                float p = shFP[r*KF + i], g = shFG[r*KF + i];
                float ns = S + p;
                if (ns >= thr) {
                    float f = (thr - S) / fmaxf(p, 1e-30f);
                    f = fminf(fmaxf(f, 0.f), 1.f);
                    G += f * g;
                    done = true;
                } else { S = ns; G += g; }
            }
        }
        float gl = G;                    // g_tail (unnormalized: scale cancels)
        float gh = gts - gl;             // g_head
        float akl = (gh*fkl + gl*rkl) / gts;
        unsafeAtomicAdd(out, akl * (1.0f/(float)DNUM));
    }
}

extern "C" void kernel_launch(void* const* d_in, const int* in_sizes, int n_in,
                              void* d_out, int out_size, void* d_ws, size_t ws_size,
                              hipStream_t stream) {
    const float* h1 = (const float*)d_in[0];
    const float* e1 = (const float*)d_in[1];
    const float* h3 = (const float*)d_in[2];
    const float* e3 = (const float*)d_in[3];
    hipMemsetAsync(d_out, 0, sizeof(float), stream);   // capture-safe
    akl_rows<<<GRID, NT, 0, stream>>>(h1, e1, h3, e3, (float*)d_out);
}